// Round 1
// baseline (544.447 us; speedup 1.0000x reference)
//
#include <hip/hip_runtime.h>
#include <cstdint>
#include <cstddef>

#define TB 4
#define TC 512
#define TT 2304
#define TH 16
#define TD 32
#define TW 19
#define WOVR 9
#define EPSLN 1e-5f
#define SCALE 0.17677669529663687f   // 1/sqrt(32)

// ---------------- mask expansion (storage-format agnostic) ----------------
// mask[b][t] = t < length_b with length_b >= T/2, so mask[0][0..1] == true.
// int32 storage: first word == 1. bool-byte storage: first word == 0x01010101.
// float storage: first word == 0x3f800000.
__global__ void k_expand_mask(const unsigned char* __restrict__ mraw,
                              float* __restrict__ mf) {
  int i = blockIdx.x * blockDim.x + threadIdx.x;
  if (i >= TB * TT) return;
  uint32_t w0 = *(const uint32_t*)mraw;
  bool on;
  if (w0 == 1u) {                       // int32
    on = ((const int*)mraw)[i] != 0;
  } else if (w0 == 0x01010101u) {       // bool bytes
    on = mraw[i] != 0;
  } else {                              // float
    on = ((const float*)mraw)[i] != 0.0f;
  }
  mf[i] = on ? 1.0f : 0.0f;
}

// ---------------- fused depthwise conv3 + mask + LayerNorm(C) ----------------
// one block per (b,t); 512 threads = one channel each
__global__ __launch_bounds__(512) void k_conv_ln(
    const float* __restrict__ x, const float* __restrict__ wconv,
    const float* __restrict__ gamma, const float* __restrict__ beta,
    const float* __restrict__ mf, float* __restrict__ out) {
  const int bt = blockIdx.x;
  const int b = bt / TT, t = bt - b * TT;
  const int c = threadIdx.x;
  const float* xp = x + ((size_t)b * TC + c) * TT + t;
  float xm1 = (t > 0)      ? xp[-1] : 0.0f;
  float x0  = xp[0];
  float xp1 = (t < TT - 1) ? xp[1]  : 0.0f;
  const float m = mf[b * TT + t];
  float y = (wconv[c * 3 + 0] * xm1 + wconv[c * 3 + 1] * x0 +
             wconv[c * 3 + 2] * xp1) * m;

  // reduction: wave shuffle then LDS partials
  float s = y, s2 = y * y;
  #pragma unroll
  for (int off = 32; off > 0; off >>= 1) {
    s  += __shfl_down(s, off, 64);
    s2 += __shfl_down(s2, off, 64);
  }
  __shared__ float ps[8], ps2[8];
  const int wid = c >> 6;
  if ((c & 63) == 0) { ps[wid] = s; ps2[wid] = s2; }
  __syncthreads();
  float sum = 0.0f, sum2 = 0.0f;
  #pragma unroll
  for (int i = 0; i < 8; i++) { sum += ps[i]; sum2 += ps2[i]; }
  const float mean = sum * (1.0f / TC);
  const float var  = sum2 * (1.0f / TC) - mean * mean;
  const float r    = rsqrtf(var + EPSLN);
  out[((size_t)b * TC + c) * TT + t] = (y - mean) * r * gamma[c] + beta[c];
}

// ---------------- tiled fp32 GEMM: Out[b,o,t] = sum_c W[o,c]*In[b,c,t] + bias[o]
// optional final mask multiply (for proj). BM=BN=64, BK=16, 256 thr, 4x4/thread.
#define BM 64
#define BN 64
#define BK 16
__global__ __launch_bounds__(256) void k_gemm(
    const float* __restrict__ W, const float* __restrict__ bias,
    const float* __restrict__ In, float* __restrict__ Out,
    const float* __restrict__ mf /* nullable */) {
  const int b  = blockIdx.z;
  const int m0 = blockIdx.y * BM;
  const int n0 = blockIdx.x * BN;
  const float* Inb = In + (size_t)b * TC * TT;
  float* Outb      = Out + (size_t)b * TC * TT;
  __shared__ float Ws[BK][BM];
  __shared__ float Xs[BK][BN];
  const int tid = threadIdx.x;
  const int tx = tid & 15, ty = tid >> 4;
  const int wm = tid >> 2;
  const int wk = (tid & 3) << 2;
  const int xk = tid >> 4;
  const int xn = (tid & 15) << 2;
  float acc[4][4] = {{0.f,0.f,0.f,0.f},{0.f,0.f,0.f,0.f},
                     {0.f,0.f,0.f,0.f},{0.f,0.f,0.f,0.f}};
  for (int k0 = 0; k0 < TC; k0 += BK) {
    float4 wv = *(const float4*)(W + (size_t)(m0 + wm) * TC + k0 + wk);
    Ws[wk + 0][wm] = wv.x; Ws[wk + 1][wm] = wv.y;
    Ws[wk + 2][wm] = wv.z; Ws[wk + 3][wm] = wv.w;
    *(float4*)&Xs[xk][xn] =
        *(const float4*)(Inb + (size_t)(k0 + xk) * TT + n0 + xn);
    __syncthreads();
    #pragma unroll
    for (int k = 0; k < BK; k++) {
      float a0 = Ws[k][ty * 4 + 0], a1 = Ws[k][ty * 4 + 1];
      float a2 = Ws[k][ty * 4 + 2], a3 = Ws[k][ty * 4 + 3];
      float q0 = Xs[k][tx * 4 + 0], q1 = Xs[k][tx * 4 + 1];
      float q2 = Xs[k][tx * 4 + 2], q3 = Xs[k][tx * 4 + 3];
      acc[0][0] += a0 * q0; acc[0][1] += a0 * q1; acc[0][2] += a0 * q2; acc[0][3] += a0 * q3;
      acc[1][0] += a1 * q0; acc[1][1] += a1 * q1; acc[1][2] += a1 * q2; acc[1][3] += a1 * q3;
      acc[2][0] += a2 * q0; acc[2][1] += a2 * q1; acc[2][2] += a2 * q2; acc[2][3] += a2 * q3;
      acc[3][0] += a3 * q0; acc[3][1] += a3 * q1; acc[3][2] += a3 * q2; acc[3][3] += a3 * q3;
    }
    __syncthreads();
  }
  #pragma unroll
  for (int i = 0; i < 4; i++) {
    const int o = m0 + ty * 4 + i;
    const float bi = bias[o];
    #pragma unroll
    for (int j = 0; j < 4; j++) {
      const int n = n0 + tx * 4 + j;
      float v = acc[i][j] + bi;
      if (mf) v *= mf[b * TT + n];
      Outb[(size_t)o * TT + n] = v;
    }
  }
}

// ---------------- banded attention: one thread per (b,h,t) ----------------
__global__ __launch_bounds__(256) void k_attn(
    const float* __restrict__ Q, const float* __restrict__ K,
    const float* __restrict__ V, const float* __restrict__ mf,
    float* __restrict__ Out) {
  const int idx = blockIdx.x * blockDim.x + threadIdx.x;
  if (idx >= TB * TH * TT) return;
  const int t  = idx % TT;
  const int bh = idx / TT;
  const int h = bh % TH, b = bh / TH;
  const size_t base = ((size_t)b * TC + h * TD) * TT;

  float q[TD];
  #pragma unroll
  for (int d = 0; d < TD; d++) q[d] = Q[base + (size_t)d * TT + t];

  float s[TW];
  float smax = -1e30f;
  #pragma unroll
  for (int j = 0; j < TW; j++) {
    const int tk = t + j - WOVR;
    float sv = -1e30f;
    if (tk >= 0 && tk < TT) {
      const float* kp = K + base + tk;
      float acc = 0.0f;
      #pragma unroll
      for (int d = 0; d < TD; d++) acc += q[d] * kp[(size_t)d * TT];
      sv = acc * SCALE + (mf[b * TT + tk] != 0.0f ? 0.0f : -1e4f);
    }
    s[j] = sv;
    smax = fmaxf(smax, sv);
  }
  float denom = 0.0f;
  #pragma unroll
  for (int j = 0; j < TW; j++) {
    float e = __expf(s[j] - smax);   // out-of-range: exp(-1e30) -> 0
    s[j] = e;
    denom += e;
  }
  const float inv = 1.0f / denom;
  const float qm = mf[b * TT + t];
  float o[TD] = {};
  #pragma unroll
  for (int j = 0; j < TW; j++) {
    const int tk = t + j - WOVR;
    if (tk >= 0 && tk < TT) {
      const float* vp = V + base + tk;
      #pragma unroll
      for (int d = 0; d < TD; d++) o[d] += s[j] * vp[(size_t)d * TT];
    }
  }
  const float sc = inv * qm;
  #pragma unroll
  for (int d = 0; d < TD; d++) Out[base + (size_t)d * TT + t] = o[d] * sc;
}

// ---------------- mask tail (second tuple output) ----------------
__global__ void k_mask_tail(const float* __restrict__ mf, float* __restrict__ out) {
  const int i = blockIdx.x * blockDim.x + threadIdx.x;
  if (i < TB * TT) out[(size_t)TB * TC * TT + i] = mf[i];
}

extern "C" void kernel_launch(void* const* d_in, const int* in_sizes, int n_in,
                              void* d_out, int out_size, void* d_ws, size_t ws_size,
                              hipStream_t stream) {
  const float* x       = (const float*)d_in[0];
  const float* w_qconv = (const float*)d_in[1];
  const float* w_kconv = (const float*)d_in[2];
  const float* w_vconv = (const float*)d_in[3];
  const float* g_q = (const float*)d_in[4];
  const float* b_q = (const float*)d_in[5];
  const float* g_k = (const float*)d_in[6];
  const float* b_k = (const float*)d_in[7];
  const float* g_v = (const float*)d_in[8];
  const float* b_v = (const float*)d_in[9];
  const float* w_query = (const float*)d_in[10];
  const float* b_query = (const float*)d_in[11];
  const float* w_key   = (const float*)d_in[12];
  const float* b_key   = (const float*)d_in[13];
  const float* w_value = (const float*)d_in[14];
  const float* b_value = (const float*)d_in[15];
  const float* w_proj  = (const float*)d_in[16];
  const float* b_proj  = (const float*)d_in[17];
  const unsigned char* mraw = (const unsigned char*)d_in[18];
  float* out = (float*)d_out;

  float* ws = (float*)d_ws;
  const size_t NBCT = (size_t)TB * TC * TT;
  float* mf  = ws;                 // B*T floats
  float* tmp = ws + 16384;         // aligned start
  float* Qb  = tmp + NBCT;
  float* Kb  = Qb + NBCT;
  float* Vb  = Kb + NBCT;

  dim3 gsm((TB * TT + 255) / 256), bsm(256);
  k_expand_mask<<<gsm, bsm, 0, stream>>>(mraw, mf);

  dim3 gln(TB * TT), bln(512);
  dim3 gg(TT / BN, TC / BM, TB), bg(256);

  k_conv_ln<<<gln, bln, 0, stream>>>(x, w_qconv, g_q, b_q, mf, tmp);
  k_gemm<<<gg, bg, 0, stream>>>(w_query, b_query, tmp, Qb, nullptr);

  k_conv_ln<<<gln, bln, 0, stream>>>(x, w_kconv, g_k, b_k, mf, tmp);
  k_gemm<<<gg, bg, 0, stream>>>(w_key, b_key, tmp, Kb, nullptr);

  k_conv_ln<<<gln, bln, 0, stream>>>(x, w_vconv, g_v, b_v, mf, tmp);
  k_gemm<<<gg, bg, 0, stream>>>(w_value, b_value, tmp, Vb, nullptr);

  const int na = TB * TH * TT;
  k_attn<<<dim3((na + 255) / 256), dim3(256), 0, stream>>>(Qb, Kb, Vb, mf, tmp);

  k_gemm<<<gg, bg, 0, stream>>>(w_proj, b_proj, tmp, out, mf);
  k_mask_tail<<<gsm, bsm, 0, stream>>>(mf, out);
}

// Round 2
// 186.757 us; speedup vs baseline: 2.9153x; 2.9153x over previous
//
#include <hip/hip_runtime.h>
#include <cstdint>
#include <cstddef>

#define TB 4
#define TC 512
#define TT 2304
#define TH 16
#define TD 32
#define TW 19
#define WOVR 9
#define EPSLN 1e-5f
#define SCALE 0.17677669529663687f   // 1/sqrt(32)
#define MTOT (TB * TT)               // 9216 rows
#define KSZ  512

typedef __attribute__((ext_vector_type(8))) short s16x8;
typedef __attribute__((ext_vector_type(8))) unsigned short u16x8;
typedef __attribute__((ext_vector_type(4))) float f32x4;

__device__ __forceinline__ float bf2f(unsigned short u) {
  union { unsigned int i; float f; } x; x.i = ((unsigned int)u) << 16; return x.f;
}
__device__ __forceinline__ unsigned short f2bf(float f) {
  union { float f; unsigned int u; } x; x.f = f;
  unsigned int r = x.u + 0x7fffu + ((x.u >> 16) & 1u);   // RNE
  return (unsigned short)(r >> 16);
}
__device__ __forceinline__ void gload16(const void* g, void* l) {
  __builtin_amdgcn_global_load_lds(
      (const __attribute__((address_space(1))) unsigned int*)g,
      (__attribute__((address_space(3))) unsigned int*)l, 16, 0, 0);
}

// ---------------- mask expansion (storage-format agnostic) ----------------
__global__ void k_expand_mask(const unsigned char* __restrict__ mraw,
                              float* __restrict__ mf) {
  int i = blockIdx.x * blockDim.x + threadIdx.x;
  if (i >= TB * TT) return;
  uint32_t w0 = *(const uint32_t*)mraw;
  bool on;
  if (w0 == 1u)                 on = ((const int*)mraw)[i] != 0;
  else if (w0 == 0x01010101u)   on = mraw[i] != 0;
  else                          on = ((const float*)mraw)[i] != 0.0f;
  mf[i] = on ? 1.0f : 0.0f;
}

// ---------------- weights fp32 -> bf16, packed [4][512][512] ----------------
__global__ void k_wconv(const float* __restrict__ wq, const float* __restrict__ wk,
                        const float* __restrict__ wv, const float* __restrict__ wp,
                        unsigned short* __restrict__ Wbf) {
  int i = blockIdx.x * 256 + threadIdx.x;
  if (i >= 4 * TC * TC) return;
  int z = i >> 18, r = i & (TC * TC - 1);
  const float* src = (z == 0) ? wq : (z == 1) ? wk : (z == 2) ? wv : wp;
  Wbf[i] = f2bf(src[r]);
}

// ---- fused 3x (depthwise conv3 + mask + LayerNorm(C)) -> bf16 [3][B*T][C] ----
// block: (t-tile of 32) x b ; 512 threads = 16 channel-groups x 32 t-lanes
__global__ __launch_bounds__(512) void k_conv_ln_t(
    const float* __restrict__ x,
    const float* __restrict__ wq, const float* __restrict__ wk, const float* __restrict__ wv,
    const float* __restrict__ gq, const float* __restrict__ bq,
    const float* __restrict__ gk, const float* __restrict__ bk,
    const float* __restrict__ gv, const float* __restrict__ bv,
    const float* __restrict__ mf, unsigned short* __restrict__ Aall) {
  const int b = blockIdx.y;
  const int t0 = blockIdx.x * 32;
  const int tid = threadIdx.x;
  const int tt = tid & 31, cg = tid >> 5;   // cg in [0,16), 32 channels each
  __shared__ unsigned short ys[TC][33];
  __shared__ float ps[16][32], ps2[16][32];
  __shared__ float mean_s[32], rstd_s[32];

  const int tg = t0 + tt;
  const float m = mf[b * TT + tg];

  for (int z = 0; z < 3; z++) {
    const float* wc = (z == 0) ? wq : (z == 1) ? wk : wv;
    float s = 0.f, s2 = 0.f;
    for (int i = 0; i < 32; i++) {
      const int c = cg * 32 + i;
      const float* xp = x + ((size_t)(b * TC + c)) * TT + tg;
      float xm1 = (tg > 0)      ? xp[-1] : 0.f;
      float x0  = xp[0];
      float xp1 = (tg < TT - 1) ? xp[1]  : 0.f;
      float y = (wc[c * 3 + 0] * xm1 + wc[c * 3 + 1] * x0 + wc[c * 3 + 2] * xp1) * m;
      s += y; s2 += y * y;
      ys[c][tt] = f2bf(y);
    }
    ps[cg][tt] = s; ps2[cg][tt] = s2;
    __syncthreads();
    if (tid < 32) {
      float su = 0.f, su2 = 0.f;
      #pragma unroll
      for (int g = 0; g < 16; g++) { su += ps[g][tid]; su2 += ps2[g][tid]; }
      float mean = su * (1.f / TC);
      float var  = su2 * (1.f / TC) - mean * mean;
      mean_s[tid] = mean;
      rstd_s[tid] = rsqrtf(fmaxf(var, 0.f) + EPSLN);
    }
    __syncthreads();
    // write phase: 512 threads = one channel each, rows are t
    const float* gp = (z == 0) ? gq : (z == 1) ? gk : gv;
    const float* bp = (z == 0) ? bq : (z == 1) ? bk : bv;
    const float g = gp[tid], be = bp[tid];
    unsigned short* oz = Aall + ((size_t)z * MTOT + b * TT + t0) * TC + tid;
    for (int r = 0; r < 32; r++) {
      float y = bf2f(ys[tid][r]);
      oz[(size_t)r * TC] = f2bf((y - mean_s[r]) * rstd_s[r] * g + be);
    }
    __syncthreads();
  }
}

// ---------------- MFMA GEMM: D[m][n] = sum_k A[m][k] * W[n][k] (+bias[n]) ----
// A: [MTOT][512] bf16 row-major (t-major activations), W: [512][512] bf16.
// 128x128 tile, 4 waves (64x64 each), K-step 32, global_load_lds w=16,
// XOR chunk swizzle ((row>>1)&3) for 2-way-max LDS read conflicts.
template<int F32OUT>
__global__ __launch_bounds__(256) void k_gemm_mfma(
    const unsigned short* __restrict__ Abase, const unsigned short* __restrict__ Wbase,
    const float* __restrict__ bq, const float* __restrict__ bk, const float* __restrict__ bv,
    unsigned short* __restrict__ obf, float* __restrict__ of32) {
  const int z = blockIdx.z;
  const unsigned short* A = Abase + (size_t)z * MTOT * KSZ;
  const unsigned short* W = Wbase + (size_t)z * KSZ * KSZ;
  const float* bias = (z == 0) ? bq : (z == 1) ? bk : bv;
  const int m0 = blockIdx.y * 128;
  const int n0 = blockIdx.x * 128;
  __shared__ unsigned short As[128 * 32];
  __shared__ unsigned short Bs[128 * 32];
  const int tid = threadIdx.x;
  const int l = tid & 63, l15 = l & 15, l4 = l >> 4;
  const int wid = tid >> 6, wm = wid >> 1, wn = wid & 1;
  // staging: 512 16B-chunks per tile, 2 per thread; swizzled global chunk
  const int r0 = tid >> 2;
  const int c0 = (tid & 3) ^ ((r0 >> 1) & 3);
  const int r1 = r0 + 64;
  const int c1 = (tid & 3) ^ ((r1 >> 1) & 3);
  // fragment LDS offsets (elements)
  int offA[4], offB[4];
  #pragma unroll
  for (int i = 0; i < 4; i++) {
    int ra = wm * 64 + i * 16 + l15;
    offA[i] = (ra * 4 + (l4 ^ ((ra >> 1) & 3))) * 8;
    int rb = wn * 64 + i * 16 + l15;
    offB[i] = (rb * 4 + (l4 ^ ((rb >> 1) & 3))) * 8;
  }
  f32x4 acc[4][4] = {};
  for (int k0 = 0; k0 < KSZ; k0 += 32) {
    gload16(A + (size_t)(m0 + r0) * KSZ + k0 + c0 * 8, As + tid * 8);
    gload16(A + (size_t)(m0 + r1) * KSZ + k0 + c1 * 8, As + (tid + 256) * 8);
    gload16(W + (size_t)(n0 + r0) * KSZ + k0 + c0 * 8, Bs + tid * 8);
    gload16(W + (size_t)(n0 + r1) * KSZ + k0 + c1 * 8, Bs + (tid + 256) * 8);
    __syncthreads();
    s16x8 av[4], bw[4];
    #pragma unroll
    for (int i = 0; i < 4; i++) {
      av[i] = *(const s16x8*)(As + offA[i]);
      bw[i] = *(const s16x8*)(Bs + offB[i]);
    }
    #pragma unroll
    for (int mi = 0; mi < 4; mi++)
      #pragma unroll
      for (int nj = 0; nj < 4; nj++)
        acc[mi][nj] = __builtin_amdgcn_mfma_f32_16x16x32_bf16(av[mi], bw[nj], acc[mi][nj], 0, 0, 0);
    __syncthreads();
  }
  // epilogue: D row=(l>>4)*4+r (m), col=l&15 (n)
  unsigned short* O = obf ? obf + (size_t)z * MTOT * KSZ : nullptr;
  #pragma unroll
  for (int nj = 0; nj < 4; nj++) {
    const int col = n0 + wn * 64 + nj * 16 + l15;
    const float bi = bias[col];
    #pragma unroll
    for (int mi = 0; mi < 4; mi++) {
      const int mrow = m0 + wm * 64 + mi * 16 + l4 * 4;
      #pragma unroll
      for (int r = 0; r < 4; r++) {
        float v = acc[mi][nj][r] + bi;
        if (F32OUT) of32[(size_t)(mrow + r) * KSZ + col] = v;
        else        O[(size_t)(mrow + r) * KSZ + col] = f2bf(v);
      }
    }
  }
}

// ---------------- banded attention on [B*T][C] bf16 layout ----------------
__global__ __launch_bounds__(256) void k_attn_t(const unsigned short* __restrict__ QKV,
                                                const float* __restrict__ mf,
                                                unsigned short* __restrict__ AO) {
  const int idx = blockIdx.x * 256 + threadIdx.x;
  if (idx >= TB * TH * TT) return;
  const int t = idx % TT;
  const int bh = idx / TT;
  const int h = bh & 15, b = bh >> 4;
  const size_t SZ = (size_t)MTOT * KSZ;
  const unsigned short* Kp = QKV + SZ;
  const unsigned short* Vp = QKV + 2 * SZ;
  const size_t rowbase = ((size_t)(b * TT + t)) * TC + h * TD;
  float q[TD];
  #pragma unroll
  for (int c = 0; c < 4; c++) {
    u16x8 v = *(const u16x8*)(QKV + rowbase + c * 8);
    #pragma unroll
    for (int j = 0; j < 8; j++) q[c * 8 + j] = bf2f(v[j]);
  }
  float e[TW];
  float smax = -3.0e38f;
  #pragma unroll
  for (int j = 0; j < TW; j++) {
    const int tk = t + j - WOVR;
    float sv = -3.0e38f;
    if (tk >= 0 && tk < TT) {
      const unsigned short* kr = Kp + ((size_t)(b * TT + tk)) * TC + h * TD;
      float acc = 0.f;
      #pragma unroll
      for (int c = 0; c < 4; c++) {
        u16x8 v = *(const u16x8*)(kr + c * 8);
        #pragma unroll
        for (int jj = 0; jj < 8; jj++) acc += q[c * 8 + jj] * bf2f(v[jj]);
      }
      sv = acc * SCALE + (mf[b * TT + tk] != 0.f ? 0.f : -1e4f);
    }
    e[j] = sv;
    smax = fmaxf(smax, sv);
  }
  float den = 0.f;
  #pragma unroll
  for (int j = 0; j < TW; j++) {
    float ev = (e[j] > -1.0e38f) ? __expf(e[j] - smax) : 0.f;
    e[j] = ev; den += ev;
  }
  float o[TD] = {};
  #pragma unroll
  for (int j = 0; j < TW; j++) {
    const int tk = t + j - WOVR;
    if (tk >= 0 && tk < TT) {
      const unsigned short* vr = Vp + ((size_t)(b * TT + tk)) * TC + h * TD;
      #pragma unroll
      for (int c = 0; c < 4; c++) {
        u16x8 v = *(const u16x8*)(vr + c * 8);
        #pragma unroll
        for (int jj = 0; jj < 8; jj++) o[c * 8 + jj] += e[j] * bf2f(v[jj]);
      }
    }
  }
  const float sc = (1.f / den) * mf[b * TT + t];
  unsigned short* op = AO + rowbase;
  #pragma unroll
  for (int c = 0; c < 4; c++) {
    u16x8 v;
    #pragma unroll
    for (int j = 0; j < 8; j++) v[j] = f2bf(o[c * 8 + j] * sc);
    *(u16x8*)(op + c * 8) = v;
  }
}

// ---------------- transpose [B*T][C] f32 -> [B][C][T] f32, apply mask ----------
__global__ __launch_bounds__(256) void k_transpose_mask(const float* __restrict__ P,
                                                        const float* __restrict__ mf,
                                                        float* __restrict__ out) {
  __shared__ float tile[32][33];
  const int t0 = blockIdx.x * 32, o0 = blockIdx.y * 32, b = blockIdx.z;
  const int tx = threadIdx.x & 31, ty = threadIdx.x >> 5;
  #pragma unroll
  for (int i = 0; i < 4; i++) {
    int t = t0 + ty + i * 8;
    tile[ty + i * 8][tx] = P[((size_t)(b * TT + t)) * TC + o0 + tx];
  }
  __syncthreads();
  const float m = mf[b * TT + t0 + tx];
  #pragma unroll
  for (int i = 0; i < 4; i++) {
    int o = o0 + ty + i * 8;
    out[((size_t)(b * TC + o)) * TT + t0 + tx] = tile[tx][ty + i * 8] * m;
  }
}

// ---------------- mask tail (second tuple output) ----------------
__global__ void k_mask_tail(const float* __restrict__ mf, float* __restrict__ out) {
  const int i = blockIdx.x * blockDim.x + threadIdx.x;
  if (i < TB * TT) out[(size_t)TB * TC * TT + i] = mf[i];
}

extern "C" void kernel_launch(void* const* d_in, const int* in_sizes, int n_in,
                              void* d_out, int out_size, void* d_ws, size_t ws_size,
                              hipStream_t stream) {
  const float* x       = (const float*)d_in[0];
  const float* w_qconv = (const float*)d_in[1];
  const float* w_kconv = (const float*)d_in[2];
  const float* w_vconv = (const float*)d_in[3];
  const float* g_q = (const float*)d_in[4];
  const float* b_q = (const float*)d_in[5];
  const float* g_k = (const float*)d_in[6];
  const float* b_k = (const float*)d_in[7];
  const float* g_v = (const float*)d_in[8];
  const float* b_v = (const float*)d_in[9];
  const float* w_query = (const float*)d_in[10];
  const float* b_query = (const float*)d_in[11];
  const float* w_key   = (const float*)d_in[12];
  const float* b_key   = (const float*)d_in[13];
  const float* w_value = (const float*)d_in[14];
  const float* b_value = (const float*)d_in[15];
  const float* w_proj  = (const float*)d_in[16];
  const float* b_proj  = (const float*)d_in[17];
  const unsigned char* mraw = (const unsigned char*)d_in[18];
  float* out = (float*)d_out;

  uint8_t* w8 = (uint8_t*)d_ws;
  float* mf            = (float*)w8;                                   // 36 KB
  unsigned short* Wbf  = (unsigned short*)(w8 + (1ull << 20));         // 2 MB
  unsigned short* Aall = (unsigned short*)(w8 + (4ull << 20));         // 28.3 MB
  float* P             = (float*)(w8 + (4ull << 20));                  // alias Aall (dead by then)
  unsigned short* QKV  = (unsigned short*)(w8 + (34ull << 20));        // 28.3 MB
  unsigned short* AO   = (unsigned short*)(w8 + (63ull << 20));        // 9.4 MB

  k_expand_mask<<<dim3((TB * TT + 255) / 256), dim3(256), 0, stream>>>(mraw, mf);
  k_wconv<<<dim3((4 * TC * TC + 255) / 256), dim3(256), 0, stream>>>(
      w_query, w_key, w_value, w_proj, Wbf);
  k_conv_ln_t<<<dim3(TT / 32, TB), dim3(512), 0, stream>>>(
      x, w_qconv, w_kconv, w_vconv, g_q, b_q, g_k, b_k, g_v, b_v, mf, Aall);
  k_gemm_mfma<0><<<dim3(4, MTOT / 128, 3), dim3(256), 0, stream>>>(
      Aall, Wbf, b_query, b_key, b_value, QKV, nullptr);
  k_attn_t<<<dim3((TB * TH * TT + 255) / 256), dim3(256), 0, stream>>>(QKV, mf, AO);
  k_gemm_mfma<1><<<dim3(4, MTOT / 128, 1), dim3(256), 0, stream>>>(
      AO, Wbf + 3 * TC * TC, b_proj, b_proj, b_proj, nullptr, P);
  k_transpose_mask<<<dim3(TT / 32, TC / 32, TB), dim3(256), 0, stream>>>(P, mf, out);
  k_mask_tail<<<dim3((TB * TT + 255) / 256), dim3(256), 0, stream>>>(mf, out);
}

// Round 3
// 117.453 us; speedup vs baseline: 4.6355x; 1.5901x over previous
//
#include <hip/hip_runtime.h>
#include <cstdint>
#include <cstddef>

#define TB 4
#define TC 512
#define TT 2304
#define TH 16
#define TD 32
#define TW 19
#define WOVR 9
#define EPSLN 1e-5f
#define SCALE 0.17677669529663687f   // 1/sqrt(32)
#define MTOT (TB * TT)               // 9216 rows
#define KSZ  512

typedef __attribute__((ext_vector_type(8))) short s16x8;
typedef __attribute__((ext_vector_type(8))) unsigned short u16x8;
typedef __attribute__((ext_vector_type(4))) float f32x4;

__device__ __forceinline__ float bf2f(unsigned short u) {
  union { unsigned int i; float f; } x; x.i = ((unsigned int)u) << 16; return x.f;
}
__device__ __forceinline__ unsigned short f2bf(float f) {
  union { float f; unsigned int u; } x; x.f = f;
  unsigned int r = x.u + 0x7fffu + ((x.u >> 16) & 1u);   // RNE
  return (unsigned short)(r >> 16);
}
__device__ __forceinline__ void gload16(const void* g, void* l) {
  __builtin_amdgcn_global_load_lds(
      (const __attribute__((address_space(1))) unsigned int*)g,
      (__attribute__((address_space(3))) unsigned int*)l, 16, 0, 0);
}

// ---------------- mask expansion (storage-format agnostic) ----------------
__global__ void k_expand_mask(const unsigned char* __restrict__ mraw,
                              float* __restrict__ mf) {
  int i = blockIdx.x * blockDim.x + threadIdx.x;
  if (i >= TB * TT) return;
  uint32_t w0 = *(const uint32_t*)mraw;
  bool on;
  if (w0 == 1u)                 on = ((const int*)mraw)[i] != 0;
  else if (w0 == 0x01010101u)   on = mraw[i] != 0;
  else                          on = ((const float*)mraw)[i] != 0.0f;
  mf[i] = on ? 1.0f : 0.0f;
}

// ---------------- weights fp32 -> bf16, packed [4][512][512] ----------------
__global__ void k_wconv(const float* __restrict__ wq, const float* __restrict__ wk,
                        const float* __restrict__ wv, const float* __restrict__ wp,
                        unsigned short* __restrict__ Wbf) {
  int i = blockIdx.x * 256 + threadIdx.x;
  if (i >= 4 * TC * TC) return;
  int z = i >> 18, r = i & (TC * TC - 1);
  const float* src = (z == 0) ? wq : (z == 1) ? wk : (z == 2) ? wv : wp;
  Wbf[i] = f2bf(src[r]);
}

// ---- fused 3x (depthwise conv3 + mask + LayerNorm(C)) -> bf16 [3][B*T][C] ----
// block = 16 t's x b; 512 threads = 32 cgroups x 16 t-lanes; x read ONCE.
__global__ __launch_bounds__(512) void k_conv_ln_t(
    const float* __restrict__ x,
    const float* __restrict__ wq, const float* __restrict__ wk, const float* __restrict__ wv,
    const float* __restrict__ gq, const float* __restrict__ bq,
    const float* __restrict__ gk, const float* __restrict__ bk,
    const float* __restrict__ gv, const float* __restrict__ bv,
    const float* __restrict__ mf, unsigned short* __restrict__ Aall) {
  const int b = blockIdx.y;
  const int t0 = blockIdx.x * 16;
  const int tid = threadIdx.x;
  const int tt = tid & 15, cg = tid >> 4;   // cg in [0,32), 16 channels each
  const int tg = t0 + tt;
  const float m = mf[b * TT + tg];
  __shared__ float ps[3][32][16], ps2[3][32][16];
  __shared__ float mean_s[3][16], rstd_s[3][16];

  float s0 = 0.f, s20 = 0.f, s1 = 0.f, s21 = 0.f, s2v = 0.f, s22 = 0.f;
  unsigned int yp0[8], yp1[8], yp2[8];
  #pragma unroll
  for (int i = 0; i < 16; i++) {
    const int c = cg * 16 + i;
    const float* xp = x + ((size_t)(b * TC + c)) * TT + tg;
    const float xm1 = (tg > 0)      ? xp[-1] : 0.f;
    const float x0  = xp[0];
    const float xp1 = (tg < TT - 1) ? xp[1]  : 0.f;
    const float yq = (wq[c*3] * xm1 + wq[c*3+1] * x0 + wq[c*3+2] * xp1) * m;
    const float yk = (wk[c*3] * xm1 + wk[c*3+1] * x0 + wk[c*3+2] * xp1) * m;
    const float yv = (wv[c*3] * xm1 + wv[c*3+1] * x0 + wv[c*3+2] * xp1) * m;
    s0 += yq; s20 += yq * yq;
    s1 += yk; s21 += yk * yk;
    s2v += yv; s22 += yv * yv;
    const unsigned int hq = f2bf(yq), hk = f2bf(yk), hv = f2bf(yv);
    if ((i & 1) == 0) { yp0[i>>1] = hq; yp1[i>>1] = hk; yp2[i>>1] = hv; }
    else { yp0[i>>1] |= hq << 16; yp1[i>>1] |= hk << 16; yp2[i>>1] |= hv << 16; }
  }
  ps[0][cg][tt] = s0; ps2[0][cg][tt] = s20;
  ps[1][cg][tt] = s1; ps2[1][cg][tt] = s21;
  ps[2][cg][tt] = s2v; ps2[2][cg][tt] = s22;
  __syncthreads();
  if (tid < 48) {
    const int z = tid >> 4, tl = tid & 15;
    float su = 0.f, su2 = 0.f;
    #pragma unroll
    for (int g = 0; g < 32; g++) { su += ps[z][g][tl]; su2 += ps2[z][g][tl]; }
    const float mean = su * (1.f / TC);
    const float var  = su2 * (1.f / TC) - mean * mean;
    mean_s[z][tl] = mean;
    rstd_s[z][tl] = rsqrtf(fmaxf(var, 0.f) + EPSLN);
  }
  __syncthreads();

  #pragma unroll
  for (int z = 0; z < 3; z++) {
    const unsigned int* yp = (z == 0) ? yp0 : (z == 1) ? yp1 : yp2;
    const float* gp = (z == 0) ? gq : (z == 1) ? gk : gv;
    const float* bp = (z == 0) ? bq : (z == 1) ? bk : bv;
    const float mean = mean_s[z][tt], rs = rstd_s[z][tt];
    unsigned short tmp[16];
    #pragma unroll
    for (int i = 0; i < 16; i++) {
      const int c = cg * 16 + i;
      const unsigned short hb =
          (unsigned short)((i & 1) ? (yp[i>>1] >> 16) : (yp[i>>1] & 0xffffu));
      tmp[i] = f2bf((bf2f(hb) - mean) * rs * gp[c] + bp[c]);
    }
    unsigned short* oz = Aall + ((size_t)z * MTOT + b * TT + tg) * TC + cg * 16;
    *(u16x8*)(oz)     = *(const u16x8*)(tmp);
    *(u16x8*)(oz + 8) = *(const u16x8*)(tmp + 8);
  }
}

// ---------------- MFMA GEMM: D[m][n] = sum_k A[m][k] * W[n][k] (+bias[n]) ----
// F32OUT=0: write bf16 [bt][512].  F32OUT=1 (proj): transpose in LDS,
// apply mask, write f32 [B][C][T] directly.
template<int F32OUT>
__global__ __launch_bounds__(256) void k_gemm_mfma(
    const unsigned short* __restrict__ Abase, const unsigned short* __restrict__ Wbase,
    const float* __restrict__ bq, const float* __restrict__ bk, const float* __restrict__ bv,
    unsigned short* __restrict__ obf, float* __restrict__ of32,
    const float* __restrict__ mf) {
  const int z = blockIdx.z;
  const unsigned short* A = Abase + (size_t)z * MTOT * KSZ;
  const unsigned short* W = Wbase + (size_t)z * KSZ * KSZ;
  const float* bias = (z == 0) ? bq : (z == 1) ? bk : bv;
  const int m0 = blockIdx.y * 128;
  const int n0 = blockIdx.x * 128;
  __shared__ __align__(16) char smem_raw[32 * 132 * 4];   // >= 16KB staging
  unsigned short* As = (unsigned short*)smem_raw;
  unsigned short* Bs = As + 128 * 32;
  const int tid = threadIdx.x;
  const int l = tid & 63, l15 = l & 15, l4 = l >> 4;
  const int wid = tid >> 6, wm = wid >> 1, wn = wid & 1;
  const int r0 = tid >> 2;
  const int c0 = (tid & 3) ^ ((r0 >> 1) & 3);
  const int r1 = r0 + 64;
  const int c1 = (tid & 3) ^ ((r1 >> 1) & 3);
  int offA[4], offB[4];
  #pragma unroll
  for (int i = 0; i < 4; i++) {
    int ra = wm * 64 + i * 16 + l15;
    offA[i] = (ra * 4 + (l4 ^ ((ra >> 1) & 3))) * 8;
    int rb = wn * 64 + i * 16 + l15;
    offB[i] = (rb * 4 + (l4 ^ ((rb >> 1) & 3))) * 8;
  }
  f32x4 acc[4][4] = {};
  for (int k0 = 0; k0 < KSZ; k0 += 32) {
    gload16(A + (size_t)(m0 + r0) * KSZ + k0 + c0 * 8, As + tid * 8);
    gload16(A + (size_t)(m0 + r1) * KSZ + k0 + c1 * 8, As + (tid + 256) * 8);
    gload16(W + (size_t)(n0 + r0) * KSZ + k0 + c0 * 8, Bs + tid * 8);
    gload16(W + (size_t)(n0 + r1) * KSZ + k0 + c1 * 8, Bs + (tid + 256) * 8);
    __syncthreads();
    s16x8 av[4], bw[4];
    #pragma unroll
    for (int i = 0; i < 4; i++) {
      av[i] = *(const s16x8*)(As + offA[i]);
      bw[i] = *(const s16x8*)(Bs + offB[i]);
    }
    #pragma unroll
    for (int mi = 0; mi < 4; mi++)
      #pragma unroll
      for (int nj = 0; nj < 4; nj++)
        acc[mi][nj] = __builtin_amdgcn_mfma_f32_16x16x32_bf16(av[mi], bw[nj], acc[mi][nj], 0, 0, 0);
    __syncthreads();
  }
  if (!F32OUT) {
    unsigned short* O = obf + (size_t)z * MTOT * KSZ;
    #pragma unroll
    for (int nj = 0; nj < 4; nj++) {
      const int col = n0 + wn * 64 + nj * 16 + l15;
      const float bi = bias[col];
      #pragma unroll
      for (int mi = 0; mi < 4; mi++) {
        const int mrow = m0 + wm * 64 + mi * 16 + l4 * 4;
        #pragma unroll
        for (int r = 0; r < 4; r++)
          O[(size_t)(mrow + r) * KSZ + col] = f2bf(acc[mi][nj][r] + bi);
      }
    }
  } else {
    // transpose 32-col chunks via LDS, apply mask, write [B][C][T]
    const int bb = m0 / TT;
    const int tloc0 = m0 - bb * TT;
    float* tb = (float*)smem_raw;            // [32][132]
    for (int c = 0; c < 4; c++) {
      if (wn == (c >> 1)) {
        #pragma unroll
        for (int njl = 0; njl < 2; njl++) {
          const int nj = (c & 1) * 2 + njl;
          const int col = n0 + wn * 64 + nj * 16 + l15;
          const float bi = bias[col];
          const int cl = njl * 16 + l15;
          #pragma unroll
          for (int mi = 0; mi < 4; mi++)
            #pragma unroll
            for (int r = 0; r < 4; r++)
              tb[cl * 132 + wm * 64 + mi * 16 + l4 * 4 + r] = acc[mi][nj][r] + bi;
        }
      }
      __syncthreads();
      const int ol = tid >> 3, part = tid & 7;
      const int o = n0 + c * 32 + ol;
      #pragma unroll
      for (int g = 0; g < 4; g++) {
        const int tl = part * 16 + g * 4;
        float4 v  = *(const float4*)&tb[ol * 132 + tl];
        float4 mm = *(const float4*)&mf[m0 + tl];
        v.x *= mm.x; v.y *= mm.y; v.z *= mm.z; v.w *= mm.w;
        *(float4*)&of32[((size_t)(bb * TC + o)) * TT + tloc0 + tl] = v;
      }
      __syncthreads();
    }
  }
}

// ---------------- banded attention, LDS-staged K/V, d-split x2 ----------------
#define AROWS (128 + 2 * WOVR)   // 146
#define ASTR  36                 // 32 data + 4 pad ushorts = 72B rows
__global__ __launch_bounds__(256) void k_attn_lds(
    const unsigned short* __restrict__ QKV, const float* __restrict__ mf,
    unsigned short* __restrict__ AO) {
  const int t0 = blockIdx.x * 128;
  const int h = blockIdx.y, b = blockIdx.z;
  const int tid = threadIdx.x;
  const int tloc = tid >> 1, half = tid & 1;
  const size_t SZ = (size_t)MTOT * KSZ;
  const unsigned short* Qp = QKV;
  const unsigned short* Kp = QKV + SZ;
  const unsigned short* Vp = QKV + 2 * SZ;
  __shared__ unsigned short Ks[AROWS * ASTR], Vs[AROWS * ASTR];
  __shared__ float mfs[AROWS];

  for (int idx = tid; idx < 2 * AROWS * 4; idx += 256) {
    const int bufv = idx >= AROWS * 4;
    const int ci = idx - bufv * AROWS * 4;
    const int r = ci >> 2, c = ci & 3;
    const int tk = t0 - WOVR + r;
    const int tkc = tk < 0 ? 0 : (tk >= TT ? TT - 1 : tk);
    const unsigned short* src =
        (bufv ? Vp : Kp) + ((size_t)(b * TT + tkc)) * TC + h * TD + c * 8;
    uint4 v = *(const uint4*)src;
    unsigned short* dst = (bufv ? Vs : Ks) + r * ASTR + c * 8;
    uint2 lo; lo.x = v.x; lo.y = v.y;
    uint2 hi; hi.x = v.z; hi.y = v.w;
    *(uint2*)dst = lo; *(uint2*)(dst + 4) = hi;
  }
  if (tid < AROWS) {
    const int tk = t0 - WOVR + tid;
    mfs[tid] = (tk >= 0 && tk < TT) ? (mf[b * TT + tk] != 0.f ? 0.f : -1e4f)
                                    : -1e30f;
  }
  __syncthreads();

  const int t = t0 + tloc;
  const float qm = mf[b * TT + t];
  float q[16];
  {
    const unsigned short* qr = Qp + ((size_t)(b * TT + t)) * TC + h * TD + half * 16;
    #pragma unroll
    for (int c = 0; c < 2; c++) {
      u16x8 v = *(const u16x8*)(qr + c * 8);
      #pragma unroll
      for (int j = 0; j < 8; j++) q[c * 8 + j] = bf2f(v[j]);
    }
  }
  float e[TW];
  float smax = -3.0e38f;
  #pragma unroll
  for (int j = 0; j < TW; j++) {
    const unsigned short* kr = Ks + (tloc + j) * ASTR + half * 16;
    float acc = 0.f;
    #pragma unroll
    for (int c = 0; c < 4; c++) {
      uint2 w = *(const uint2*)(kr + c * 4);
      acc = fmaf(q[c*4+0], bf2f((unsigned short)(w.x & 0xffffu)), acc);
      acc = fmaf(q[c*4+1], bf2f((unsigned short)(w.x >> 16)), acc);
      acc = fmaf(q[c*4+2], bf2f((unsigned short)(w.y & 0xffffu)), acc);
      acc = fmaf(q[c*4+3], bf2f((unsigned short)(w.y >> 16)), acc);
    }
    acc += __shfl_xor(acc, 1, 64);
    const float sv = acc * SCALE + mfs[tloc + j];
    e[j] = sv;
    smax = fmaxf(smax, sv);
  }
  float den = 0.f;
  #pragma unroll
  for (int j = 0; j < TW; j++) { const float ev = __expf(e[j] - smax); e[j] = ev; den += ev; }
  float o[16] = {};
  #pragma unroll
  for (int j = 0; j < TW; j++) {
    const unsigned short* vr = Vs + (tloc + j) * ASTR + half * 16;
    const float p = e[j];
    #pragma unroll
    for (int c = 0; c < 4; c++) {
      uint2 w = *(const uint2*)(vr + c * 4);
      o[c*4+0] = fmaf(p, bf2f((unsigned short)(w.x & 0xffffu)), o[c*4+0]);
      o[c*4+1] = fmaf(p, bf2f((unsigned short)(w.x >> 16)), o[c*4+1]);
      o[c*4+2] = fmaf(p, bf2f((unsigned short)(w.y & 0xffffu)), o[c*4+2]);
      o[c*4+3] = fmaf(p, bf2f((unsigned short)(w.y >> 16)), o[c*4+3]);
    }
  }
  const float sc = qm / den;
  unsigned short tmp[16];
  #pragma unroll
  for (int i = 0; i < 16; i++) tmp[i] = f2bf(o[i] * sc);
  unsigned short* op = AO + ((size_t)(b * TT + t)) * TC + h * TD + half * 16;
  *(u16x8*)(op)     = *(const u16x8*)(tmp);
  *(u16x8*)(op + 8) = *(const u16x8*)(tmp + 8);
}

// ---------------- mask tail (second tuple output) ----------------
__global__ void k_mask_tail(const float* __restrict__ mf, float* __restrict__ out) {
  const int i = blockIdx.x * blockDim.x + threadIdx.x;
  if (i < TB * TT) out[(size_t)TB * TC * TT + i] = mf[i];
}

extern "C" void kernel_launch(void* const* d_in, const int* in_sizes, int n_in,
                              void* d_out, int out_size, void* d_ws, size_t ws_size,
                              hipStream_t stream) {
  const float* x       = (const float*)d_in[0];
  const float* w_qconv = (const float*)d_in[1];
  const float* w_kconv = (const float*)d_in[2];
  const float* w_vconv = (const float*)d_in[3];
  const float* g_q = (const float*)d_in[4];
  const float* b_q = (const float*)d_in[5];
  const float* g_k = (const float*)d_in[6];
  const float* b_k = (const float*)d_in[7];
  const float* g_v = (const float*)d_in[8];
  const float* b_v = (const float*)d_in[9];
  const float* w_query = (const float*)d_in[10];
  const float* b_query = (const float*)d_in[11];
  const float* w_key   = (const float*)d_in[12];
  const float* b_key   = (const float*)d_in[13];
  const float* w_value = (const float*)d_in[14];
  const float* b_value = (const float*)d_in[15];
  const float* w_proj  = (const float*)d_in[16];
  const float* b_proj  = (const float*)d_in[17];
  const unsigned char* mraw = (const unsigned char*)d_in[18];
  float* out = (float*)d_out;

  uint8_t* w8 = (uint8_t*)d_ws;
  float* mf            = (float*)w8;                                   // 36 KB
  unsigned short* Wbf  = (unsigned short*)(w8 + (1ull << 20));         // 2 MB
  unsigned short* Aall = (unsigned short*)(w8 + (4ull << 20));         // 28.3 MB
  unsigned short* QKV  = (unsigned short*)(w8 + (34ull << 20));        // 28.3 MB
  unsigned short* AO   = (unsigned short*)(w8 + (63ull << 20));        // 9.4 MB

  k_expand_mask<<<dim3((TB * TT + 255) / 256), dim3(256), 0, stream>>>(mraw, mf);
  k_wconv<<<dim3((4 * TC * TC + 255) / 256), dim3(256), 0, stream>>>(
      w_query, w_key, w_value, w_proj, Wbf);
  k_conv_ln_t<<<dim3(TT / 16, TB), dim3(512), 0, stream>>>(
      x, w_qconv, w_kconv, w_vconv, g_q, b_q, g_k, b_k, g_v, b_v, mf, Aall);
  k_gemm_mfma<0><<<dim3(4, MTOT / 128, 3), dim3(256), 0, stream>>>(
      Aall, Wbf, b_query, b_key, b_value, QKV, nullptr, mf);
  k_attn_lds<<<dim3(TT / 128, TH, TB), dim3(256), 0, stream>>>(QKV, mf, AO);
  k_gemm_mfma<1><<<dim3(4, MTOT / 128, 1), dim3(256), 0, stream>>>(
      AO, Wbf + 3 * TC * TC, b_proj, b_proj, b_proj, nullptr, out, mf);
  k_mask_tail<<<dim3((TB * TT + 255) / 256), dim3(256), 0, stream>>>(mf, out);
}

// Round 4
// 109.413 us; speedup vs baseline: 4.9761x; 1.0735x over previous
//
#include <hip/hip_runtime.h>
#include <cstdint>
#include <cstddef>

#define TB 4
#define TC 512
#define TT 2304
#define TH 16
#define TD 32
#define TW 19
#define WOVR 9
#define EPSLN 1e-5f
#define SCALE 0.17677669529663687f   // 1/sqrt(32)
#define MTOT (TB * TT)               // 9216 rows
#define KSZ  512

typedef __attribute__((ext_vector_type(8))) short s16x8;
typedef __attribute__((ext_vector_type(8))) unsigned short u16x8;
typedef __attribute__((ext_vector_type(4))) float f32x4;

__device__ __forceinline__ float bf2f(unsigned short u) {
  union { unsigned int i; float f; } x; x.i = ((unsigned int)u) << 16; return x.f;
}
__device__ __forceinline__ unsigned short f2bf(float f) {
  union { float f; unsigned int u; } x; x.f = f;
  unsigned int r = x.u + 0x7fffu + ((x.u >> 16) & 1u);   // RNE
  return (unsigned short)(r >> 16);
}
__device__ __forceinline__ void gload16(const void* g, void* l) {
  __builtin_amdgcn_global_load_lds(
      (const __attribute__((address_space(1))) unsigned int*)g,
      (__attribute__((address_space(3))) unsigned int*)l, 16, 0, 0);
}

// ------- prep: mask expand + weight bf16 pack + mask tail (one kernel) -------
__global__ void k_prep(const unsigned char* __restrict__ mraw,
                       const float* __restrict__ wq, const float* __restrict__ wk,
                       const float* __restrict__ wv, const float* __restrict__ wp,
                       unsigned short* __restrict__ Wbf,
                       float* __restrict__ mf, float* __restrict__ out) {
  const int i = blockIdx.x * 256 + threadIdx.x;
  if (i < 4 * TC * TC) {
    const int z = i >> 18, r = i & (TC * TC - 1);
    const float* src = (z == 0) ? wq : (z == 1) ? wk : (z == 2) ? wv : wp;
    Wbf[i] = f2bf(src[r]);
  }
  if (i < TB * TT) {
    const uint32_t w0 = *(const uint32_t*)mraw;
    bool on;
    if (w0 == 1u)                 on = ((const int*)mraw)[i] != 0;
    else if (w0 == 0x01010101u)   on = mraw[i] != 0;
    else                          on = ((const float*)mraw)[i] != 0.0f;
    const float v = on ? 1.0f : 0.0f;
    mf[i] = v;
    out[(size_t)TB * TC * TT + i] = v;   // tuple output #2
  }
}

// ---- fused 3x (depthwise conv3 + mask + LayerNorm(C)) -> bf16 [3][B*T][C] ----
// block = 16 t's x b; 512 threads = 32 cgroups x 16 t-lanes; x read ONCE.
__global__ __launch_bounds__(512) void k_conv_ln_t(
    const float* __restrict__ x,
    const float* __restrict__ wq, const float* __restrict__ wk, const float* __restrict__ wv,
    const float* __restrict__ gq, const float* __restrict__ bq,
    const float* __restrict__ gk, const float* __restrict__ bk,
    const float* __restrict__ gv, const float* __restrict__ bv,
    const float* __restrict__ mf, unsigned short* __restrict__ Aall) {
  const int b = blockIdx.y;
  const int t0 = blockIdx.x * 16;
  const int tid = threadIdx.x;
  const int tt = tid & 15, cg = tid >> 4;   // cg in [0,32), 16 channels each
  const int tg = t0 + tt;
  const float m = mf[b * TT + tg];
  __shared__ float ps[3][32][16], ps2[3][32][16];
  __shared__ float mean_s[3][16], rstd_s[3][16];

  float s0 = 0.f, s20 = 0.f, s1 = 0.f, s21 = 0.f, s2v = 0.f, s22 = 0.f;
  unsigned int yp0[8], yp1[8], yp2[8];
  #pragma unroll
  for (int i = 0; i < 16; i++) {
    const int c = cg * 16 + i;
    const float* xp = x + ((size_t)(b * TC + c)) * TT + tg;
    const float xm1 = (tg > 0)      ? xp[-1] : 0.f;
    const float x0  = xp[0];
    const float xp1 = (tg < TT - 1) ? xp[1]  : 0.f;
    const float yq = (wq[c*3] * xm1 + wq[c*3+1] * x0 + wq[c*3+2] * xp1) * m;
    const float yk = (wk[c*3] * xm1 + wk[c*3+1] * x0 + wk[c*3+2] * xp1) * m;
    const float yv = (wv[c*3] * xm1 + wv[c*3+1] * x0 + wv[c*3+2] * xp1) * m;
    s0 += yq; s20 += yq * yq;
    s1 += yk; s21 += yk * yk;
    s2v += yv; s22 += yv * yv;
    const unsigned int hq = f2bf(yq), hk = f2bf(yk), hv = f2bf(yv);
    if ((i & 1) == 0) { yp0[i>>1] = hq; yp1[i>>1] = hk; yp2[i>>1] = hv; }
    else { yp0[i>>1] |= hq << 16; yp1[i>>1] |= hk << 16; yp2[i>>1] |= hv << 16; }
  }
  ps[0][cg][tt] = s0; ps2[0][cg][tt] = s20;
  ps[1][cg][tt] = s1; ps2[1][cg][tt] = s21;
  ps[2][cg][tt] = s2v; ps2[2][cg][tt] = s22;
  __syncthreads();
  if (tid < 48) {
    const int z = tid >> 4, tl = tid & 15;
    float su = 0.f, su2 = 0.f;
    #pragma unroll
    for (int g = 0; g < 32; g++) { su += ps[z][g][tl]; su2 += ps2[z][g][tl]; }
    const float mean = su * (1.f / TC);
    const float var  = su2 * (1.f / TC) - mean * mean;
    mean_s[z][tl] = mean;
    rstd_s[z][tl] = rsqrtf(fmaxf(var, 0.f) + EPSLN);
  }
  __syncthreads();

  #pragma unroll
  for (int z = 0; z < 3; z++) {
    const unsigned int* yp = (z == 0) ? yp0 : (z == 1) ? yp1 : yp2;
    const float* gp = (z == 0) ? gq : (z == 1) ? gk : gv;
    const float* bp = (z == 0) ? bq : (z == 1) ? bk : bv;
    const float mean = mean_s[z][tt], rs = rstd_s[z][tt];
    unsigned short tmp[16];
    #pragma unroll
    for (int i = 0; i < 16; i++) {
      const int c = cg * 16 + i;
      const unsigned short hb =
          (unsigned short)((i & 1) ? (yp[i>>1] >> 16) : (yp[i>>1] & 0xffffu));
      tmp[i] = f2bf((bf2f(hb) - mean) * rs * gp[c] + bp[c]);
    }
    unsigned short* oz = Aall + ((size_t)z * MTOT + b * TT + tg) * TC + cg * 16;
    *(u16x8*)(oz)     = *(const u16x8*)(tmp);
    *(u16x8*)(oz + 8) = *(const u16x8*)(tmp + 8);
  }
}

// ---------------- MFMA GEMM: D[m][n] = sum_k A[m][k] * W[n][k] (+bias[n]) ----
// Double-buffered LDS, ONE barrier per K-step (stage next -> compute cur ->
// __syncthreads drains vmcnt+lgkm). F32OUT=1 (proj): LDS-transpose epilogue,
// apply mask, write f32 [B][C][T] directly.
template<int F32OUT>
__global__ __launch_bounds__(256) void k_gemm_mfma(
    const unsigned short* __restrict__ Abase, const unsigned short* __restrict__ Wbase,
    const float* __restrict__ bq, const float* __restrict__ bk, const float* __restrict__ bv,
    unsigned short* __restrict__ obf, float* __restrict__ of32,
    const float* __restrict__ mf) {
  const int z = blockIdx.z;
  const unsigned short* A = Abase + (size_t)z * MTOT * KSZ;
  const unsigned short* W = Wbase + (size_t)z * KSZ * KSZ;
  const float* bias = (z == 0) ? bq : (z == 1) ? bk : bv;
  const int m0 = blockIdx.y * 128;
  const int n0 = blockIdx.x * 128;
  // [0]=A buf0, [1]=A buf1, [2]=B buf0, [3]=B buf1  (4 x 8KB = 32KB)
  __shared__ __align__(16) unsigned short smem[4][128 * 32];
  const int tid = threadIdx.x;
  const int l = tid & 63, l15 = l & 15, l4 = l >> 4;
  const int wid = tid >> 6, wm = wid >> 1, wn = wid & 1;
  const int r0 = tid >> 2;
  const int c0 = (tid & 3) ^ ((r0 >> 1) & 3);
  const int r1 = r0 + 64;
  const int c1 = (tid & 3) ^ ((r1 >> 1) & 3);
  int offA[4], offB[4];
  #pragma unroll
  for (int i = 0; i < 4; i++) {
    int ra = wm * 64 + i * 16 + l15;
    offA[i] = (ra * 4 + (l4 ^ ((ra >> 1) & 3))) * 8;
    int rb = wn * 64 + i * 16 + l15;
    offB[i] = (rb * 4 + (l4 ^ ((rb >> 1) & 3))) * 8;
  }
  const size_t ga0 = (size_t)(m0 + r0) * KSZ + c0 * 8;
  const size_t ga1 = (size_t)(m0 + r1) * KSZ + c1 * 8;
  const size_t gb0 = (size_t)(n0 + r0) * KSZ + c0 * 8;
  const size_t gb1 = (size_t)(n0 + r1) * KSZ + c1 * 8;

  #define STAGE(buf, kk)                                            \
    do {                                                            \
      unsigned short* Ad = &smem[0][0] + (buf) * (128 * 32);        \
      unsigned short* Bd = &smem[2][0] + (buf) * (128 * 32);        \
      gload16(A + ga0 + (kk), Ad + tid * 8);                        \
      gload16(A + ga1 + (kk), Ad + (tid + 256) * 8);                \
      gload16(W + gb0 + (kk), Bd + tid * 8);                        \
      gload16(W + gb1 + (kk), Bd + (tid + 256) * 8);                \
    } while (0)

  f32x4 acc[4][4] = {};
  STAGE(0, 0);
  __syncthreads();               // drain vmcnt: buf0 ready
  int cur = 0;
  for (int k0 = 0; k0 < KSZ; k0 += 32) {
    if (k0 + 32 < KSZ) STAGE(cur ^ 1, k0 + 32);   // prefetch next tile
    const unsigned short* Ac = &smem[0][0] + cur * (128 * 32);
    const unsigned short* Bc = &smem[2][0] + cur * (128 * 32);
    s16x8 av[4], bw[4];
    #pragma unroll
    for (int i = 0; i < 4; i++) {
      av[i] = *(const s16x8*)(Ac + offA[i]);
      bw[i] = *(const s16x8*)(Bc + offB[i]);
    }
    #pragma unroll
    for (int mi = 0; mi < 4; mi++)
      #pragma unroll
      for (int nj = 0; nj < 4; nj++)
        acc[mi][nj] = __builtin_amdgcn_mfma_f32_16x16x32_bf16(av[mi], bw[nj], acc[mi][nj], 0, 0, 0);
    __syncthreads();             // reads of cur done + next buf landed
    cur ^= 1;
  }
  #undef STAGE

  if (!F32OUT) {
    unsigned short* O = obf + (size_t)z * MTOT * KSZ;
    #pragma unroll
    for (int nj = 0; nj < 4; nj++) {
      const int col = n0 + wn * 64 + nj * 16 + l15;
      const float bi = bias[col];
      #pragma unroll
      for (int mi = 0; mi < 4; mi++) {
        const int mrow = m0 + wm * 64 + mi * 16 + l4 * 4;
        #pragma unroll
        for (int r = 0; r < 4; r++)
          O[(size_t)(mrow + r) * KSZ + col] = f2bf(acc[mi][nj][r] + bi);
      }
    }
  } else {
    // transpose 32-col chunks via LDS, apply mask, write [B][C][T]
    const int bb = m0 / TT;
    const int tloc0 = m0 - bb * TT;
    float* tb = (float*)&smem[0][0];         // [32][132] = 16.9KB < 32KB
    for (int c = 0; c < 4; c++) {
      if (wn == (c >> 1)) {
        #pragma unroll
        for (int njl = 0; njl < 2; njl++) {
          const int nj = (c & 1) * 2 + njl;
          const int col = n0 + wn * 64 + nj * 16 + l15;
          const float bi = bias[col];
          const int cl = njl * 16 + l15;
          #pragma unroll
          for (int mi = 0; mi < 4; mi++)
            #pragma unroll
            for (int r = 0; r < 4; r++)
              tb[cl * 132 + wm * 64 + mi * 16 + l4 * 4 + r] = acc[mi][nj][r] + bi;
        }
      }
      __syncthreads();
      const int ol = tid >> 3, part = tid & 7;
      const int o = n0 + c * 32 + ol;
      #pragma unroll
      for (int g = 0; g < 4; g++) {
        const int tl = part * 16 + g * 4;
        float4 v  = *(const float4*)&tb[ol * 132 + tl];
        float4 mm = *(const float4*)&mf[m0 + tl];
        v.x *= mm.x; v.y *= mm.y; v.z *= mm.z; v.w *= mm.w;
        *(float4*)&of32[((size_t)(bb * TC + o)) * TT + tloc0 + tl] = v;
      }
      __syncthreads();
    }
  }
}

// ---------------- banded attention, LDS-staged K/V, d-split x2 ----------------
#define AROWS (128 + 2 * WOVR)   // 146
#define ASTR  36                 // 32 data + 4 pad ushorts = 72B rows
__global__ __launch_bounds__(256) void k_attn_lds(
    const unsigned short* __restrict__ QKV, const float* __restrict__ mf,
    unsigned short* __restrict__ AO) {
  const int t0 = blockIdx.x * 128;
  const int h = blockIdx.y, b = blockIdx.z;
  const int tid = threadIdx.x;
  const int tloc = tid >> 1, half = tid & 1;
  const size_t SZ = (size_t)MTOT * KSZ;
  const unsigned short* Qp = QKV;
  const unsigned short* Kp = QKV + SZ;
  const unsigned short* Vp = QKV + 2 * SZ;
  __shared__ unsigned short Ks[AROWS * ASTR], Vs[AROWS * ASTR];
  __shared__ float mfs[AROWS];

  for (int idx = tid; idx < 2 * AROWS * 4; idx += 256) {
    const int bufv = idx >= AROWS * 4;
    const int ci = idx - bufv * AROWS * 4;
    const int r = ci >> 2, c = ci & 3;
    const int tk = t0 - WOVR + r;
    const int tkc = tk < 0 ? 0 : (tk >= TT ? TT - 1 : tk);
    const unsigned short* src =
        (bufv ? Vp : Kp) + ((size_t)(b * TT + tkc)) * TC + h * TD + c * 8;
    uint4 v = *(const uint4*)src;
    unsigned short* dst = (bufv ? Vs : Ks) + r * ASTR + c * 8;
    uint2 lo; lo.x = v.x; lo.y = v.y;
    uint2 hi; hi.x = v.z; hi.y = v.w;
    *(uint2*)dst = lo; *(uint2*)(dst + 4) = hi;
  }
  if (tid < AROWS) {
    const int tk = t0 - WOVR + tid;
    mfs[tid] = (tk >= 0 && tk < TT) ? (mf[b * TT + tk] != 0.f ? 0.f : -1e4f)
                                    : -1e30f;
  }
  __syncthreads();

  const int t = t0 + tloc;
  const float qm = mf[b * TT + t];
  float q[16];
  {
    const unsigned short* qr = Qp + ((size_t)(b * TT + t)) * TC + h * TD + half * 16;
    #pragma unroll
    for (int c = 0; c < 2; c++) {
      u16x8 v = *(const u16x8*)(qr + c * 8);
      #pragma unroll
      for (int j = 0; j < 8; j++) q[c * 8 + j] = bf2f(v[j]);
    }
  }
  float e[TW];
  float smax = -3.0e38f;
  #pragma unroll
  for (int j = 0; j < TW; j++) {
    const unsigned short* kr = Ks + (tloc + j) * ASTR + half * 16;
    float acc = 0.f;
    #pragma unroll
    for (int c = 0; c < 4; c++) {
      uint2 w = *(const uint2*)(kr + c * 4);
      acc = fmaf(q[c*4+0], bf2f((unsigned short)(w.x & 0xffffu)), acc);
      acc = fmaf(q[c*4+1], bf2f((unsigned short)(w.x >> 16)), acc);
      acc = fmaf(q[c*4+2], bf2f((unsigned short)(w.y & 0xffffu)), acc);
      acc = fmaf(q[c*4+3], bf2f((unsigned short)(w.y >> 16)), acc);
    }
    acc += __shfl_xor(acc, 1, 64);
    const float sv = acc * SCALE + mfs[tloc + j];
    e[j] = sv;
    smax = fmaxf(smax, sv);
  }
  float den = 0.f;
  #pragma unroll
  for (int j = 0; j < TW; j++) { const float ev = __expf(e[j] - smax); e[j] = ev; den += ev; }
  float o[16] = {};
  #pragma unroll
  for (int j = 0; j < TW; j++) {
    const unsigned short* vr = Vs + (tloc + j) * ASTR + half * 16;
    const float p = e[j];
    #pragma unroll
    for (int c = 0; c < 4; c++) {
      uint2 w = *(const uint2*)(vr + c * 4);
      o[c*4+0] = fmaf(p, bf2f((unsigned short)(w.x & 0xffffu)), o[c*4+0]);
      o[c*4+1] = fmaf(p, bf2f((unsigned short)(w.x >> 16)), o[c*4+1]);
      o[c*4+2] = fmaf(p, bf2f((unsigned short)(w.y & 0xffffu)), o[c*4+2]);
      o[c*4+3] = fmaf(p, bf2f((unsigned short)(w.y >> 16)), o[c*4+3]);
    }
  }
  const float sc = qm / den;
  unsigned short tmp[16];
  #pragma unroll
  for (int i = 0; i < 16; i++) tmp[i] = f2bf(o[i] * sc);
  unsigned short* op = AO + ((size_t)(b * TT + t)) * TC + h * TD + half * 16;
  *(u16x8*)(op)     = *(const u16x8*)(tmp);
  *(u16x8*)(op + 8) = *(const u16x8*)(tmp + 8);
}

extern "C" void kernel_launch(void* const* d_in, const int* in_sizes, int n_in,
                              void* d_out, int out_size, void* d_ws, size_t ws_size,
                              hipStream_t stream) {
  const float* x       = (const float*)d_in[0];
  const float* w_qconv = (const float*)d_in[1];
  const float* w_kconv = (const float*)d_in[2];
  const float* w_vconv = (const float*)d_in[3];
  const float* g_q = (const float*)d_in[4];
  const float* b_q = (const float*)d_in[5];
  const float* g_k = (const float*)d_in[6];
  const float* b_k = (const float*)d_in[7];
  const float* g_v = (const float*)d_in[8];
  const float* b_v = (const float*)d_in[9];
  const float* w_query = (const float*)d_in[10];
  const float* b_query = (const float*)d_in[11];
  const float* w_key   = (const float*)d_in[12];
  const float* b_key   = (const float*)d_in[13];
  const float* w_value = (const float*)d_in[14];
  const float* b_value = (const float*)d_in[15];
  const float* w_proj  = (const float*)d_in[16];
  const float* b_proj  = (const float*)d_in[17];
  const unsigned char* mraw = (const unsigned char*)d_in[18];
  float* out = (float*)d_out;

  uint8_t* w8 = (uint8_t*)d_ws;
  float* mf            = (float*)w8;                                   // 36 KB
  unsigned short* Wbf  = (unsigned short*)(w8 + (1ull << 20));         // 2 MB
  unsigned short* Aall = (unsigned short*)(w8 + (4ull << 20));         // 28.3 MB
  unsigned short* QKV  = (unsigned short*)(w8 + (34ull << 20));        // 28.3 MB
  unsigned short* AO   = (unsigned short*)(w8 + (63ull << 20));        // 9.4 MB

  k_prep<<<dim3((4 * TC * TC + 255) / 256), dim3(256), 0, stream>>>(
      mraw, w_query, w_key, w_value, w_proj, Wbf, mf, out);
  k_conv_ln_t<<<dim3(TT / 16, TB), dim3(512), 0, stream>>>(
      x, w_qconv, w_kconv, w_vconv, g_q, b_q, g_k, b_k, g_v, b_v, mf, Aall);
  k_gemm_mfma<0><<<dim3(4, MTOT / 128, 3), dim3(256), 0, stream>>>(
      Aall, Wbf, b_query, b_key, b_value, QKV, nullptr, mf);
  k_attn_lds<<<dim3(TT / 128, TH, TB), dim3(256), 0, stream>>>(QKV, mf, AO);
  k_gemm_mfma<1><<<dim3(4, MTOT / 128, 1), dim3(256), 0, stream>>>(
      AO, Wbf + 3 * TC * TC, b_proj, b_proj, b_proj, nullptr, out, mf);
}